// Round 4
// baseline (624.695 us; speedup 1.0000x reference)
//
#include <hip/hip_runtime.h>
#include <stdint.h>

#define NB 2
#define NS 2048
#define NH 32
#define NKV 8
#define ND 128
#define NWIN 1024
// scale * log2(e) : scores tracked in exp2 domain
#define SCALE2 (0.08838834764831845f * 1.4426950408889634f)

typedef __bf16 bf16x8 __attribute__((ext_vector_type(8)));
typedef float f32x4 __attribute__((ext_vector_type(4)));
typedef unsigned short u16x4 __attribute__((ext_vector_type(4)));
typedef unsigned short u16x8 __attribute__((ext_vector_type(8)));
typedef unsigned int u32x2 __attribute__((ext_vector_type(2)));

union Frag { u16x8 u; bf16x8 b; u32x2 w[2]; __bf16 e[8]; };
union BF4 { u16x4 u; __bf16 b[4]; };

// Block: 256 threads = 4 waves; block = (b, h, 64-row q-tile); wave w owns 16 q-rows.
// SWAPPED-OPERAND scheme (everything transposed; softmax fully in-register):
//   QK:  s[f] = mfma(A=K_frag, B=Q_frag)  ->  S^T: lane owns q = l15,
//        k = sigma(f*16 + lg*4 + r)  (16 scores in-register per lane).
//   K rows staged PERMUTED: LDS row rk holds logical k-row sigma(rk), with
//   sigma chosen so lane's held k-set == PV B-frag k-set:
//        sigma bits: k = [r4 r3 r2 r5 r1 r0]  (rk = [r5..r0])
//        => held k = (f&1)*32 + lg*8 + (f>>1)*4 + r
//   P -> PV B-frag: pure in-lane bf16 packing, ZERO cross-lane exchange:
//        pb[ks].j = { f=ks, r=j } (j<4) ; { f=ks+2, r=j-4 } (j>=4)
//   PV:  acc[c] = mfma(A=V_frag(tr-read), B=pb)  ->  O^T: lane owns
//        O[q=l15][d=c*16+lg*4+r]; rescale and epilogue are lane-local.
// Softmax row-reduce: in-lane over 16 + shfl_xor(16) + shfl_xor(32) (4 shfls
// total per tile vs 64 in the unswapped scheme; P_lds eliminated entirely).
// V in LDS: tr-subtiled for ds_read_b64_tr_b16 (per-lane addr = base + lane*8);
//   read r at byte c*2048 + r*512 gives lane l elem j:
//   V[32*(r>>1) + 8*(l>>4) + 4*(r&1) + j][c*16 + (l&15)].
__global__ __launch_bounds__(256, 4)
void attn_fwd(const float* __restrict__ qg, const float* __restrict__ kg,
              const float* __restrict__ vg, float* __restrict__ og) {
  __shared__ unsigned short k_lds[64 * 128];     // 16 KB (permuted rows, XOR swizzle)
  __shared__ unsigned short v_lds[64 * 128];     // 16 KB (tr-subtiled)

  const int tid = threadIdx.x;
  const int w = tid >> 6;
  const int lane = tid & 63;
  const int l15 = lane & 15;
  const int lg = lane >> 4;

  const int bid = blockIdx.x;
  const int h = bid & 31;                 // h fastest: GQA group shares K/V in L2
  const int qt = 31 - ((bid >> 5) & 31);  // long blocks dispatch first
  const int b = bid >> 10;
  const int hkv = h >> 2;
  const float slope2 = exp2f(-0.25f * (float)(h + 1)) * 1.4426950408889634f;
  const int q0 = qt * 64;
  const int qi = q0 + w * 16 + l15;       // this lane's q-row

  // ---- Q fragments (fp32 -> bf16), 4 K-steps over D=128 ----
  u16x8 qf[4];
  {
    const float* qp = qg + (size_t)(b * NS + qi) * (NH * ND) + h * ND;
#pragma unroll
    for (int ks = 0; ks < 4; ++ks) {
      const int dbase = ks * 32 + lg * 8;
      float4 f0 = *(const float4*)(qp + dbase);
      float4 f1 = *(const float4*)(qp + dbase + 4);
      Frag q_;
      q_.e[0] = (__bf16)f0.x; q_.e[1] = (__bf16)f0.y;
      q_.e[2] = (__bf16)f0.z; q_.e[3] = (__bf16)f0.w;
      q_.e[4] = (__bf16)f1.x; q_.e[5] = (__bf16)f1.y;
      q_.e[6] = (__bf16)f1.z; q_.e[7] = (__bf16)f1.w;
      qf[ks] = q_.u;
    }
  }

  float m_r = -1e30f, l_r = 0.f;
  f32x4 acc[8];
#pragma unroll
  for (int c = 0; c < 8; ++c) {
    acc[c][0] = 0.f; acc[c][1] = 0.f; acc[c][2] = 0.f; acc[c][3] = 0.f;
  }

  const int srow = tid >> 5;        // 0..7
  const int sdb = (tid & 31) * 4;   // 0..124
  const int sc = sdb >> 4;
  const int sx = sdb & 15;
  float4 kreg[8], vreg[8];

  const int t0 = (q0 >= NWIN) ? ((q0 - NWIN) >> 6) : 0;
  const int t1 = q0 >> 6;

  auto load_tile = [&](int t) {
    const int kvbase = t * 64;
#pragma unroll
    for (int it = 0; it < 8; ++it) {
      const size_t go =
          (size_t)(b * NS + kvbase + it * 8 + srow) * (NKV * ND) + hkv * ND + sdb;
      kreg[it] = *(const float4*)(kg + go);
      vreg[it] = *(const float4*)(vg + go);
    }
  };

  load_tile(t0);

  for (int t = t0; t <= t1; ++t) {
    const int kvbase = t * 64;
    __syncthreads();   // prior tile's LDS reads complete before overwrite
    // ---- convert + write staged regs to LDS ----
#pragma unroll
    for (int it = 0; it < 8; ++it) {
      const int row = it * 8 + srow;                       // logical k-row
      BF4 ku, vu;
      ku.b[0] = (__bf16)kreg[it].x; ku.b[1] = (__bf16)kreg[it].y;
      ku.b[2] = (__bf16)kreg[it].z; ku.b[3] = (__bf16)kreg[it].w;
      vu.b[0] = (__bf16)vreg[it].x; vu.b[1] = (__bf16)vreg[it].y;
      vu.b[2] = (__bf16)vreg[it].z; vu.b[3] = (__bf16)vreg[it].w;
      // K: inverse row-perm: rk = [k2 k5 k4 k3 k1 k0]
      const int rk = ((row & 4) << 3) | ((row & 56) >> 1) | (row & 3);
      const int kb = (rk * 256 + sdb * 2) ^ ((rk & 7) << 4);
      *(u16x4*)((char*)k_lds + kb) = ku.u;
      const int s2 = ((row >> 5) << 1) | ((row >> 2) & 1);
      const int vi = sc * 1024 + s2 * 256 + ((row >> 3) & 3) * 64 + (row & 3) * 16 + sx;
      *(u16x4*)(&v_lds[vi]) = vu.u;
    }
    __syncthreads();
    if (t < t1) load_tile(t + 1);   // prefetch; first use is next iter's convert

    // ---- QK^T (swapped): s[f] = S^T frag, lane owns q=l15 ----
    f32x4 s[4];
#pragma unroll
    for (int f = 0; f < 4; ++f) { s[f][0] = 0.f; s[f][1] = 0.f; s[f][2] = 0.f; s[f][3] = 0.f; }
    const int xo = (l15 & 7) << 4;
#pragma unroll
    for (int ks = 0; ks < 4; ++ks) {
      const int db2 = ks * 64 + lg * 16;
      Frag qa; qa.u = qf[ks];
#pragma unroll
      for (int f = 0; f < 4; ++f) {
        Frag kb;
        kb.u = *(u16x8*)((char*)k_lds + (((f * 16 + l15) * 256 + db2) ^ xo));
        s[f] = __builtin_amdgcn_mfma_f32_16x16x32_bf16(kb.b, qa.b, s[f], 0, 0, 0);
      }
    }

    // ---- in-register online softmax (lane owns q=l15; k = kvbase+koff) ----
    // koff(f,lg,r) = (f&1)*32 + lg*8 + (f>>1)*4 + r
    const int dbse = qi - kvbase - lg * 8;
    float sv[4][4];
#pragma unroll
    for (int f = 0; f < 4; ++f) {
#pragma unroll
      for (int r = 0; r < 4; ++r) {
        const int koff = ((f & 1) << 5) + ((f >> 1) << 2) + r;
        const int d = dbse - koff;                      // qi - j
        const float val = fmaf(s[f][r], SCALE2, -slope2 * (float)d);
        sv[f][r] = ((unsigned)d <= (unsigned)NWIN) ? val : -1e30f;
      }
    }
    float tm = fmaxf(fmaxf(sv[0][0], sv[0][1]), fmaxf(sv[0][2], sv[0][3]));
#pragma unroll
    for (int f = 1; f < 4; ++f)
      tm = fmaxf(tm, fmaxf(fmaxf(sv[f][0], sv[f][1]), fmaxf(sv[f][2], sv[f][3])));
    tm = fmaxf(tm, __shfl_xor(tm, 16, 64));
    tm = fmaxf(tm, __shfl_xor(tm, 32, 64));
    const float newm = fmaxf(m_r, tm);
    const float fac = __builtin_amdgcn_exp2f(m_r - newm);
    m_r = newm;
    float rs = 0.f;
    Frag pb0, pb1;
#pragma unroll
    for (int f = 0; f < 4; ++f) {
      float e0 = __builtin_amdgcn_exp2f(sv[f][0] - m_r);
      float e1 = __builtin_amdgcn_exp2f(sv[f][1] - m_r);
      float e2 = __builtin_amdgcn_exp2f(sv[f][2] - m_r);
      float e3 = __builtin_amdgcn_exp2f(sv[f][3] - m_r);
      rs += (e0 + e1) + (e2 + e3);
      const int base = (f >> 1) * 4;
      if (f & 1) {
        pb1.e[base + 0] = (__bf16)e0; pb1.e[base + 1] = (__bf16)e1;
        pb1.e[base + 2] = (__bf16)e2; pb1.e[base + 3] = (__bf16)e3;
      } else {
        pb0.e[base + 0] = (__bf16)e0; pb0.e[base + 1] = (__bf16)e1;
        pb0.e[base + 2] = (__bf16)e2; pb0.e[base + 3] = (__bf16)e3;
      }
    }
    rs += __shfl_xor(rs, 16, 64);
    rs += __shfl_xor(rs, 32, 64);
    l_r = l_r * fac + rs;
#pragma unroll
    for (int c = 0; c < 8; ++c) acc[c] = acc[c] * fac;

    // ---- PV (swapped): acc[c] = mfma(V_frag, pb) -> O^T ----
    const unsigned int vbase = (unsigned int)(uintptr_t)(&v_lds[0]) + lane * 8;
#pragma unroll
    for (int c = 0; c < 8; ++c) {
      u32x2 r0, r1, r2, r3;
      const unsigned int a = vbase + c * 2048;
      asm volatile("ds_read_b64_tr_b16 %0, %1" : "=v"(r0) : "v"(a));
      asm volatile("ds_read_b64_tr_b16 %0, %1 offset:512" : "=v"(r1) : "v"(a));
      asm volatile("ds_read_b64_tr_b16 %0, %1 offset:1024" : "=v"(r2) : "v"(a));
      asm volatile("ds_read_b64_tr_b16 %0, %1 offset:1536" : "=v"(r3) : "v"(a));
      asm volatile("s_waitcnt lgkmcnt(0)" ::: "memory");
      __builtin_amdgcn_sched_barrier(0);
      Frag vb0, vb1;
      vb0.w[0] = r0; vb0.w[1] = r1;   // k rows 8lg..8lg+7
      vb1.w[0] = r2; vb1.w[1] = r3;   // +32
      acc[c] = __builtin_amdgcn_mfma_f32_16x16x32_bf16(vb0.b, pb0.b, acc[c], 0, 0, 0);
      acc[c] = __builtin_amdgcn_mfma_f32_16x16x32_bf16(vb1.b, pb1.b, acc[c], 0, 0, 0);
    }
  }

  // ---- epilogue: O[q=l15][d=c*16+lg*4+r] = acc/l; float4 stores ----
  const float inv = 1.0f / l_r;
  float* op = og + (size_t)(b * NS + qi) * (NH * ND) + h * ND + lg * 4;
#pragma unroll
  for (int c = 0; c < 8; ++c) {
    f32x4 o = acc[c] * inv;
    *(f32x4*)(op + c * 16) = o;
  }
}

extern "C" void kernel_launch(void* const* d_in, const int* in_sizes, int n_in,
                              void* d_out, int out_size, void* d_ws, size_t ws_size,
                              hipStream_t stream) {
  (void)in_sizes; (void)n_in; (void)d_ws; (void)ws_size; (void)out_size;
  const float* q = (const float*)d_in[0];
  const float* k = (const float*)d_in[1];
  const float* v = (const float*)d_in[2];
  float* out = (float*)d_out;
  dim3 grid(NB * NH * (NS / 64));
  dim3 block(256);
  attn_fwd<<<grid, block, 0, stream>>>(q, k, v, out);
}

// Round 5
// 321.096 us; speedup vs baseline: 1.9455x; 1.9455x over previous
//
#include <hip/hip_runtime.h>
#include <stdint.h>

#define NB 2
#define NS 2048
#define NH 32
#define NKV 8
#define ND 128
#define NWIN 1024
// scale * log2(e) : scores tracked in exp2 domain
#define SCALE2 (0.08838834764831845f * 1.4426950408889634f)

typedef __bf16 bf16x8 __attribute__((ext_vector_type(8)));
typedef float f32x4 __attribute__((ext_vector_type(4)));
typedef unsigned short u16x4 __attribute__((ext_vector_type(4)));
typedef unsigned short u16x8 __attribute__((ext_vector_type(8)));
typedef unsigned int u32x2 __attribute__((ext_vector_type(2)));

union Frag { u16x8 u; bf16x8 b; u32x2 w[2]; __bf16 e[8]; };
union BF4 { u16x4 u; __bf16 b[4]; };

// Block: 256 threads = 4 waves; block = (b, h, 64-row q-tile); wave w owns 16 q-rows.
// SWAPPED-OPERAND scheme (everything transposed; softmax fully in-register):
//   QK:  s[f] = mfma(A=K_frag, B=Q_frag)  ->  S^T: lane owns q = l15,
//        k = sigma(f*16 + lg*4 + r)  (16 scores in-register per lane).
//   K rows staged PERMUTED: LDS row rk holds logical k-row sigma(rk), with
//   sigma chosen so lane's held k-set == PV B-frag k-set:
//        sigma bits: k = [r4 r3 r2 r5 r1 r0]  (rk = [r5..r0])
//        => held k = (f&1)*32 + lg*8 + (f>>1)*4 + r
//   P -> PV B-frag: pure in-lane bf16 packing, ZERO cross-lane exchange.
//   PV:  acc[c] = mfma(A=V_frag(tr-read), B=pb)  ->  O^T: lane owns
//        O[q=l15][d=c*16+lg*4+r]; rescale and epilogue are lane-local.
// Softmax row-reduce: in-lane over 16 + shfl_xor(16) + shfl_xor(32).
// V in LDS: tr-subtiled for ds_read_b64_tr_b16 (per-lane addr = base + lane*8).
// __launch_bounds__(256,3): VGPR cap 170. (256,4) capped at 64 -> all staging
// regs spilled to scratch: FETCH 98MB->1.3GB, dur 224->624us (Round-4 lesson).
__global__ __launch_bounds__(256, 3)
void attn_fwd(const float* __restrict__ qg, const float* __restrict__ kg,
              const float* __restrict__ vg, float* __restrict__ og) {
  __shared__ unsigned short k_lds[64 * 128];     // 16 KB (permuted rows, XOR swizzle)
  __shared__ unsigned short v_lds[64 * 128];     // 16 KB (tr-subtiled)

  const int tid = threadIdx.x;
  const int w = tid >> 6;
  const int lane = tid & 63;
  const int l15 = lane & 15;
  const int lg = lane >> 4;

  const int bid = blockIdx.x;
  const int h = bid & 31;                 // h fastest: GQA group shares K/V in L2
  const int qt = 31 - ((bid >> 5) & 31);  // long blocks dispatch first
  const int b = bid >> 10;
  const int hkv = h >> 2;
  const float slope2 = exp2f(-0.25f * (float)(h + 1)) * 1.4426950408889634f;
  const int q0 = qt * 64;
  const int qi = q0 + w * 16 + l15;       // this lane's q-row

  // ---- Q fragments (fp32 -> bf16), 4 K-steps over D=128 ----
  u16x8 qf[4];
  {
    const float* qp = qg + (size_t)(b * NS + qi) * (NH * ND) + h * ND;
#pragma unroll
    for (int ks = 0; ks < 4; ++ks) {
      const int dbase = ks * 32 + lg * 8;
      float4 f0 = *(const float4*)(qp + dbase);
      float4 f1 = *(const float4*)(qp + dbase + 4);
      Frag q_;
      q_.e[0] = (__bf16)f0.x; q_.e[1] = (__bf16)f0.y;
      q_.e[2] = (__bf16)f0.z; q_.e[3] = (__bf16)f0.w;
      q_.e[4] = (__bf16)f1.x; q_.e[5] = (__bf16)f1.y;
      q_.e[6] = (__bf16)f1.z; q_.e[7] = (__bf16)f1.w;
      qf[ks] = q_.u;
    }
  }

  float m_r = -1e30f, l_r = 0.f;
  f32x4 acc[8];
#pragma unroll
  for (int c = 0; c < 8; ++c) {
    acc[c][0] = 0.f; acc[c][1] = 0.f; acc[c][2] = 0.f; acc[c][3] = 0.f;
  }

  const int srow = tid >> 5;        // 0..7
  const int sdb = (tid & 31) * 4;   // 0..124
  const int sc = sdb >> 4;
  const int sx = sdb & 15;
  float4 kreg[8], vreg[8];

  const int t0 = (q0 >= NWIN) ? ((q0 - NWIN) >> 6) : 0;
  const int t1 = q0 >> 6;

  auto load_tile = [&](int t) {
    const int kvbase = t * 64;
#pragma unroll
    for (int it = 0; it < 8; ++it) {
      const size_t go =
          (size_t)(b * NS + kvbase + it * 8 + srow) * (NKV * ND) + hkv * ND + sdb;
      kreg[it] = *(const float4*)(kg + go);
      vreg[it] = *(const float4*)(vg + go);
    }
  };

  load_tile(t0);

  for (int t = t0; t <= t1; ++t) {
    const int kvbase = t * 64;
    __syncthreads();   // prior tile's LDS reads complete before overwrite
    // ---- convert + write staged regs to LDS ----
#pragma unroll
    for (int it = 0; it < 8; ++it) {
      const int row = it * 8 + srow;                       // logical k-row
      BF4 ku, vu;
      ku.b[0] = (__bf16)kreg[it].x; ku.b[1] = (__bf16)kreg[it].y;
      ku.b[2] = (__bf16)kreg[it].z; ku.b[3] = (__bf16)kreg[it].w;
      vu.b[0] = (__bf16)vreg[it].x; vu.b[1] = (__bf16)vreg[it].y;
      vu.b[2] = (__bf16)vreg[it].z; vu.b[3] = (__bf16)vreg[it].w;
      // K: inverse row-perm: rk = [k2 k5 k4 k3 k1 k0]
      const int rk = ((row & 4) << 3) | ((row & 56) >> 1) | (row & 3);
      const int kb = (rk * 256 + sdb * 2) ^ ((rk & 7) << 4);
      *(u16x4*)((char*)k_lds + kb) = ku.u;
      const int s2 = ((row >> 5) << 1) | ((row >> 2) & 1);
      const int vi = sc * 1024 + s2 * 256 + ((row >> 3) & 3) * 64 + (row & 3) * 16 + sx;
      *(u16x4*)(&v_lds[vi]) = vu.u;
    }
    __syncthreads();
    if (t < t1) load_tile(t + 1);   // prefetch; first use is next iter's convert

    // ---- QK^T (swapped): s[f] = S^T frag, lane owns q=l15 ----
    f32x4 s[4];
#pragma unroll
    for (int f = 0; f < 4; ++f) { s[f][0] = 0.f; s[f][1] = 0.f; s[f][2] = 0.f; s[f][3] = 0.f; }
    const int xo = (l15 & 7) << 4;
#pragma unroll
    for (int ks = 0; ks < 4; ++ks) {
      const int db2 = ks * 64 + lg * 16;
      Frag qa; qa.u = qf[ks];
#pragma unroll
      for (int f = 0; f < 4; ++f) {
        Frag kb;
        kb.u = *(u16x8*)((char*)k_lds + (((f * 16 + l15) * 256 + db2) ^ xo));
        s[f] = __builtin_amdgcn_mfma_f32_16x16x32_bf16(kb.b, qa.b, s[f], 0, 0, 0);
      }
    }

    // ---- in-register online softmax (lane owns q=l15; k = kvbase+koff) ----
    // koff(f,lg,r) = (f&1)*32 + lg*8 + (f>>1)*4 + r
    const int dbse = qi - kvbase - lg * 8;
    float sv[4][4];
#pragma unroll
    for (int f = 0; f < 4; ++f) {
#pragma unroll
      for (int r = 0; r < 4; ++r) {
        const int koff = ((f & 1) << 5) + ((f >> 1) << 2) + r;
        const int d = dbse - koff;                      // qi - j
        const float val = fmaf(s[f][r], SCALE2, -slope2 * (float)d);
        sv[f][r] = ((unsigned)d <= (unsigned)NWIN) ? val : -1e30f;
      }
    }
    float tm = fmaxf(fmaxf(sv[0][0], sv[0][1]), fmaxf(sv[0][2], sv[0][3]));
#pragma unroll
    for (int f = 1; f < 4; ++f)
      tm = fmaxf(tm, fmaxf(fmaxf(sv[f][0], sv[f][1]), fmaxf(sv[f][2], sv[f][3])));
    tm = fmaxf(tm, __shfl_xor(tm, 16, 64));
    tm = fmaxf(tm, __shfl_xor(tm, 32, 64));
    const float newm = fmaxf(m_r, tm);
    const float fac = __builtin_amdgcn_exp2f(m_r - newm);
    m_r = newm;
    float rs = 0.f;
    Frag pb0, pb1;
#pragma unroll
    for (int f = 0; f < 4; ++f) {
      float e0 = __builtin_amdgcn_exp2f(sv[f][0] - m_r);
      float e1 = __builtin_amdgcn_exp2f(sv[f][1] - m_r);
      float e2 = __builtin_amdgcn_exp2f(sv[f][2] - m_r);
      float e3 = __builtin_amdgcn_exp2f(sv[f][3] - m_r);
      rs += (e0 + e1) + (e2 + e3);
      const int base = (f >> 1) * 4;
      if (f & 1) {
        pb1.e[base + 0] = (__bf16)e0; pb1.e[base + 1] = (__bf16)e1;
        pb1.e[base + 2] = (__bf16)e2; pb1.e[base + 3] = (__bf16)e3;
      } else {
        pb0.e[base + 0] = (__bf16)e0; pb0.e[base + 1] = (__bf16)e1;
        pb0.e[base + 2] = (__bf16)e2; pb0.e[base + 3] = (__bf16)e3;
      }
    }
    rs += __shfl_xor(rs, 16, 64);
    rs += __shfl_xor(rs, 32, 64);
    l_r = l_r * fac + rs;
#pragma unroll
    for (int c = 0; c < 8; ++c) acc[c] = acc[c] * fac;

    // ---- PV (swapped): acc[c] = mfma(V_frag, pb) -> O^T ----
    const unsigned int vbase = (unsigned int)(uintptr_t)(&v_lds[0]) + lane * 8;
#pragma unroll
    for (int c = 0; c < 8; ++c) {
      u32x2 r0, r1, r2, r3;
      const unsigned int a = vbase + c * 2048;
      asm volatile("ds_read_b64_tr_b16 %0, %1" : "=v"(r0) : "v"(a));
      asm volatile("ds_read_b64_tr_b16 %0, %1 offset:512" : "=v"(r1) : "v"(a));
      asm volatile("ds_read_b64_tr_b16 %0, %1 offset:1024" : "=v"(r2) : "v"(a));
      asm volatile("ds_read_b64_tr_b16 %0, %1 offset:1536" : "=v"(r3) : "v"(a));
      asm volatile("s_waitcnt lgkmcnt(0)" ::: "memory");
      __builtin_amdgcn_sched_barrier(0);
      Frag vb0, vb1;
      vb0.w[0] = r0; vb0.w[1] = r1;   // k rows 8lg..8lg+7
      vb1.w[0] = r2; vb1.w[1] = r3;   // +32
      acc[c] = __builtin_amdgcn_mfma_f32_16x16x32_bf16(vb0.b, pb0.b, acc[c], 0, 0, 0);
      acc[c] = __builtin_amdgcn_mfma_f32_16x16x32_bf16(vb1.b, pb1.b, acc[c], 0, 0, 0);
    }
  }

  // ---- epilogue: O[q=l15][d=c*16+lg*4+r] = acc/l; float4 stores ----
  const float inv = 1.0f / l_r;
  float* op = og + (size_t)(b * NS + qi) * (NH * ND) + h * ND + lg * 4;
#pragma unroll
  for (int c = 0; c < 8; ++c) {
    f32x4 o = acc[c] * inv;
    *(f32x4*)(op + c * 16) = o;
  }
}

extern "C" void kernel_launch(void* const* d_in, const int* in_sizes, int n_in,
                              void* d_out, int out_size, void* d_ws, size_t ws_size,
                              hipStream_t stream) {
  (void)in_sizes; (void)n_in; (void)d_ws; (void)ws_size; (void)out_size;
  const float* q = (const float*)d_in[0];
  const float* k = (const float*)d_in[1];
  const float* v = (const float*)d_in[2];
  float* out = (float*)d_out;
  dim3 grid(NB * NH * (NS / 64));
  dim3 block(256);
  attn_fwd<<<grid, block, 0, stream>>>(q, k, v, out);
}

// Round 6
// 154.002 us; speedup vs baseline: 4.0564x; 2.0850x over previous
//
#include <hip/hip_runtime.h>
#include <stdint.h>

#define NB 2
#define NS 2048
#define NH 32
#define NKV 8
#define ND 128
#define NWIN 1024
// scale * log2(e) : scores tracked in exp2 domain
#define SCALE2 (0.08838834764831845f * 1.4426950408889634f)

typedef __bf16 bf16x8 __attribute__((ext_vector_type(8)));
typedef float f32x4 __attribute__((ext_vector_type(4)));
typedef unsigned short u16x4 __attribute__((ext_vector_type(4)));
typedef unsigned short u16x8 __attribute__((ext_vector_type(8)));
typedef unsigned int u32x2 __attribute__((ext_vector_type(2)));

union Frag { u16x8 u; bf16x8 b; u32x2 w[2]; __bf16 e[8]; };
union BF4 { u16x4 u; __bf16 b[4]; };

// Block: 256 threads = 4 waves; block = (b, h, 64-row q-tile); wave w owns 16 q-rows.
// SWAPPED-OPERAND scheme (everything transposed; softmax fully in-register):
//   QK:  s[f] = mfma(A=K_frag, B=Q_frag)  ->  S^T: lane owns q = l15,
//        k = sigma(f*16 + lg*4 + r)  (16 scores in-register per lane).
//   K rows staged PERMUTED so lane's held k-set == PV B-frag k-set:
//        sigma bits: k = [r4 r3 r2 r5 r1 r0]  => held k = (f&1)*32+lg*8+(f>>1)*4+r
//   P -> PV B-frag: pure in-lane bf16 packing, ZERO cross-lane exchange.
//   PV:  acc[c] = mfma(A=V_frag(tr-read), B=pb)  ->  O^T: lane owns
//        O[q=l15][d=c*16+lg*4+r]; rescale and epilogue are lane-local.
// V in LDS: tr-subtiled for ds_read_b64_tr_b16 (per-lane addr = base + lane*8).
// LAUNCH BOUNDS (measured on this toolchain): (256,N) caps VGPR at ~512/(2N):
//   arg4 -> 64 (R4: full spill, FETCH 1.3GB), arg3 -> 84 (R5: partial spill,
//   FETCH 793MB vs 98MB ideal), arg2 -> 116+ (R1/R3: no spill). Kernel needs
//   ~130 VGPRs (kreg/vreg 64 + qf 16 + acc 32 + temps) => (256,2) is the only
//   non-spilling setting.
__global__ __launch_bounds__(256, 2)
void attn_fwd(const float* __restrict__ qg, const float* __restrict__ kg,
              const float* __restrict__ vg, float* __restrict__ og) {
  __shared__ unsigned short k_lds[64 * 128];     // 16 KB (permuted rows, XOR swizzle)
  __shared__ unsigned short v_lds[64 * 128];     // 16 KB (tr-subtiled)

  const int tid = threadIdx.x;
  const int w = tid >> 6;
  const int lane = tid & 63;
  const int l15 = lane & 15;
  const int lg = lane >> 4;

  const int bid = blockIdx.x;
  const int h = bid & 31;                 // h fastest: GQA group shares K/V in L2
  const int qt = 31 - ((bid >> 5) & 31);  // long blocks dispatch first
  const int b = bid >> 10;
  const int hkv = h >> 2;
  const float slope2 = exp2f(-0.25f * (float)(h + 1)) * 1.4426950408889634f;
  const int q0 = qt * 64;
  const int qi = q0 + w * 16 + l15;       // this lane's q-row

  // ---- Q fragments (fp32 -> bf16), 4 K-steps over D=128 ----
  u16x8 qf[4];
  {
    const float* qp = qg + (size_t)(b * NS + qi) * (NH * ND) + h * ND;
#pragma unroll
    for (int ks = 0; ks < 4; ++ks) {
      const int dbase = ks * 32 + lg * 8;
      float4 f0 = *(const float4*)(qp + dbase);
      float4 f1 = *(const float4*)(qp + dbase + 4);
      Frag q_;
      q_.e[0] = (__bf16)f0.x; q_.e[1] = (__bf16)f0.y;
      q_.e[2] = (__bf16)f0.z; q_.e[3] = (__bf16)f0.w;
      q_.e[4] = (__bf16)f1.x; q_.e[5] = (__bf16)f1.y;
      q_.e[6] = (__bf16)f1.z; q_.e[7] = (__bf16)f1.w;
      qf[ks] = q_.u;
    }
  }

  float m_r = -1e30f, l_r = 0.f;
  f32x4 acc[8];
#pragma unroll
  for (int c = 0; c < 8; ++c) {
    acc[c][0] = 0.f; acc[c][1] = 0.f; acc[c][2] = 0.f; acc[c][3] = 0.f;
  }

  const int srow = tid >> 5;        // 0..7
  const int sdb = (tid & 31) * 4;   // 0..124
  const int sc = sdb >> 4;
  const int sx = sdb & 15;
  float4 kreg[8], vreg[8];

  const int t0 = (q0 >= NWIN) ? ((q0 - NWIN) >> 6) : 0;
  const int t1 = q0 >> 6;

  auto load_tile = [&](int t) {
    const int kvbase = t * 64;
#pragma unroll
    for (int it = 0; it < 8; ++it) {
      const size_t go =
          (size_t)(b * NS + kvbase + it * 8 + srow) * (NKV * ND) + hkv * ND + sdb;
      kreg[it] = *(const float4*)(kg + go);
      vreg[it] = *(const float4*)(vg + go);
    }
  };

  load_tile(t0);

  for (int t = t0; t <= t1; ++t) {
    const int kvbase = t * 64;
    __syncthreads();   // prior tile's LDS reads complete before overwrite
    // ---- convert + write staged regs to LDS ----
#pragma unroll
    for (int it = 0; it < 8; ++it) {
      const int row = it * 8 + srow;                       // logical k-row
      BF4 ku, vu;
      ku.b[0] = (__bf16)kreg[it].x; ku.b[1] = (__bf16)kreg[it].y;
      ku.b[2] = (__bf16)kreg[it].z; ku.b[3] = (__bf16)kreg[it].w;
      vu.b[0] = (__bf16)vreg[it].x; vu.b[1] = (__bf16)vreg[it].y;
      vu.b[2] = (__bf16)vreg[it].z; vu.b[3] = (__bf16)vreg[it].w;
      // K: inverse row-perm: rk = [k2 k5 k4 k3 k1 k0]
      const int rk = ((row & 4) << 3) | ((row & 56) >> 1) | (row & 3);
      const int kb = (rk * 256 + sdb * 2) ^ ((rk & 7) << 4);
      *(u16x4*)((char*)k_lds + kb) = ku.u;
      const int s2 = ((row >> 5) << 1) | ((row >> 2) & 1);
      const int vi = sc * 1024 + s2 * 256 + ((row >> 3) & 3) * 64 + (row & 3) * 16 + sx;
      *(u16x4*)(&v_lds[vi]) = vu.u;
    }
    __syncthreads();
    if (t < t1) load_tile(t + 1);   // prefetch; first use is next iter's convert

    // ---- QK^T (swapped): s[f] = S^T frag, lane owns q=l15 ----
    f32x4 s[4];
#pragma unroll
    for (int f = 0; f < 4; ++f) { s[f][0] = 0.f; s[f][1] = 0.f; s[f][2] = 0.f; s[f][3] = 0.f; }
    const int xo = (l15 & 7) << 4;
#pragma unroll
    for (int ks = 0; ks < 4; ++ks) {
      const int db2 = ks * 64 + lg * 16;
      Frag qa; qa.u = qf[ks];
#pragma unroll
      for (int f = 0; f < 4; ++f) {
        Frag kb;
        kb.u = *(u16x8*)((char*)k_lds + (((f * 16 + l15) * 256 + db2) ^ xo));
        s[f] = __builtin_amdgcn_mfma_f32_16x16x32_bf16(kb.b, qa.b, s[f], 0, 0, 0);
      }
    }

    // ---- in-register online softmax (lane owns q=l15; k = kvbase+koff) ----
    // koff(f,lg,r) = (f&1)*32 + lg*8 + (f>>1)*4 + r
    const int dbse = qi - kvbase - lg * 8;
    float sv[4][4];
#pragma unroll
    for (int f = 0; f < 4; ++f) {
#pragma unroll
      for (int r = 0; r < 4; ++r) {
        const int koff = ((f & 1) << 5) + ((f >> 1) << 2) + r;
        const int d = dbse - koff;                      // qi - j
        const float val = fmaf(s[f][r], SCALE2, -slope2 * (float)d);
        sv[f][r] = ((unsigned)d <= (unsigned)NWIN) ? val : -1e30f;
      }
    }
    float tm = fmaxf(fmaxf(sv[0][0], sv[0][1]), fmaxf(sv[0][2], sv[0][3]));
#pragma unroll
    for (int f = 1; f < 4; ++f)
      tm = fmaxf(tm, fmaxf(fmaxf(sv[f][0], sv[f][1]), fmaxf(sv[f][2], sv[f][3])));
    tm = fmaxf(tm, __shfl_xor(tm, 16, 64));
    tm = fmaxf(tm, __shfl_xor(tm, 32, 64));
    const float newm = fmaxf(m_r, tm);
    const float fac = __builtin_amdgcn_exp2f(m_r - newm);
    m_r = newm;
    float rs = 0.f;
    Frag pb0, pb1;
#pragma unroll
    for (int f = 0; f < 4; ++f) {
      float e0 = __builtin_amdgcn_exp2f(sv[f][0] - m_r);
      float e1 = __builtin_amdgcn_exp2f(sv[f][1] - m_r);
      float e2 = __builtin_amdgcn_exp2f(sv[f][2] - m_r);
      float e3 = __builtin_amdgcn_exp2f(sv[f][3] - m_r);
      rs += (e0 + e1) + (e2 + e3);
      const int base = (f >> 1) * 4;
      if (f & 1) {
        pb1.e[base + 0] = (__bf16)e0; pb1.e[base + 1] = (__bf16)e1;
        pb1.e[base + 2] = (__bf16)e2; pb1.e[base + 3] = (__bf16)e3;
      } else {
        pb0.e[base + 0] = (__bf16)e0; pb0.e[base + 1] = (__bf16)e1;
        pb0.e[base + 2] = (__bf16)e2; pb0.e[base + 3] = (__bf16)e3;
      }
    }
    rs += __shfl_xor(rs, 16, 64);
    rs += __shfl_xor(rs, 32, 64);
    l_r = l_r * fac + rs;
#pragma unroll
    for (int c = 0; c < 8; ++c) acc[c] = acc[c] * fac;

    // ---- PV (swapped): acc[c] = mfma(V_frag, pb) -> O^T ----
    const unsigned int vbase = (unsigned int)(uintptr_t)(&v_lds[0]) + lane * 8;
#pragma unroll
    for (int c = 0; c < 8; ++c) {
      u32x2 r0, r1, r2, r3;
      const unsigned int a = vbase + c * 2048;
      asm volatile("ds_read_b64_tr_b16 %0, %1" : "=v"(r0) : "v"(a));
      asm volatile("ds_read_b64_tr_b16 %0, %1 offset:512" : "=v"(r1) : "v"(a));
      asm volatile("ds_read_b64_tr_b16 %0, %1 offset:1024" : "=v"(r2) : "v"(a));
      asm volatile("ds_read_b64_tr_b16 %0, %1 offset:1536" : "=v"(r3) : "v"(a));
      asm volatile("s_waitcnt lgkmcnt(0)" ::: "memory");
      __builtin_amdgcn_sched_barrier(0);
      Frag vb0, vb1;
      vb0.w[0] = r0; vb0.w[1] = r1;   // k rows 8lg..8lg+7
      vb1.w[0] = r2; vb1.w[1] = r3;   // +32
      acc[c] = __builtin_amdgcn_mfma_f32_16x16x32_bf16(vb0.b, pb0.b, acc[c], 0, 0, 0);
      acc[c] = __builtin_amdgcn_mfma_f32_16x16x32_bf16(vb1.b, pb1.b, acc[c], 0, 0, 0);
    }
  }

  // ---- epilogue: O[q=l15][d=c*16+lg*4+r] = acc/l; float4 stores ----
  const float inv = 1.0f / l_r;
  float* op = og + (size_t)(b * NS + qi) * (NH * ND) + h * ND + lg * 4;
#pragma unroll
  for (int c = 0; c < 8; ++c) {
    f32x4 o = acc[c] * inv;
    *(f32x4*)(op + c * 16) = o;
  }
}

extern "C" void kernel_launch(void* const* d_in, const int* in_sizes, int n_in,
                              void* d_out, int out_size, void* d_ws, size_t ws_size,
                              hipStream_t stream) {
  (void)in_sizes; (void)n_in; (void)d_ws; (void)ws_size; (void)out_size;
  const float* q = (const float*)d_in[0];
  const float* k = (const float*)d_in[1];
  const float* v = (const float*)d_in[2];
  float* out = (float*)d_out;
  dim3 grid(NB * NH * (NS / 64));
  dim3 block(256);
  attn_fwd<<<grid, block, 0, stream>>>(q, k, v, out);
}